// Round 27
// baseline (34.656 us; speedup 1.0000x reference)
//
#include <hip/hip_runtime.h>

#define SENT    256
#define BATCH   64
#define WLEN    16
#define D_WORDE 300
#define D_CHARE 50
#define OUT_CH  200
#define KSIZE   3
#define NPOS    14
#define D_OUT   500
#define NWORDS  (SENT * BATCH)

// GEMM geometry (transposed): per position p, M=16 words, N=13x16=208, K=192.
// A[word][kg=kk*64+c] = emb[word][p+kk][c]; 4-row sliding window, p-PAIR ILP.
// 2-phase stage split along p: rows 0-7 staged first; rows 8-15 staged under
// compute of pp=0..1 (whose window slides touch rows <= 7 ONLY — the r26 bug
// was splitting at pp=3, letting pp=2's slide prefetch rows 8,9 pre-barrier).
// Bias folded into K: charP col63 = 1.0, WO[o][191] = conv_b[o].
#define KPAD      192
#define MPAD      208
#define CHARP_U16 (129 * 64)
#define WO_U16    (MPAD * KPAD)
#define WS_NEED   ((size_t)(CHARP_U16 + WO_U16) * 2)

#define WPB         16                 // words per block (= M of each p-GEMM)
#define TILE_U16    (WPB * 1024)       // 32 KB staging tile
#define CONV_BLOCKS (NWORDS / WPB)     // 1024 blocks x 512 threads

typedef short  short8  __attribute__((ext_vector_type(8)));
typedef ushort ushort8 __attribute__((ext_vector_type(8)));
typedef float  float4v __attribute__((ext_vector_type(4)));

#define GLOAD16(SRC, DST)                                                     \
    __builtin_amdgcn_global_load_lds(                                         \
        (const __attribute__((address_space(1))) void*)(SRC),                 \
        (__attribute__((address_space(3))) void*)(DST), 16, 0, 0)

__device__ __forceinline__ ushort f2bf(float f) {
    unsigned u = __float_as_uint(f);
    u = (u + 0x7FFFu + ((u >> 16) & 1u)) >> 16;   // RNE
    return (ushort)u;
}

// ---------- prep: bf16 char table (col63=1.0) + K-major weights (kg191=bias) ----------
__global__ void prep_kernel(const float* __restrict__ W_char,
                            const float* __restrict__ conv_w,
                            const float* __restrict__ conv_b,
                            ushort* __restrict__ ws) {
    int j = blockIdx.x * 256 + threadIdx.x;
    if (j < CHARP_U16) {
        int r = j >> 6, c = j & 63;
        ushort v = 0;
        if (r < 128) {
            if (c < D_CHARE)      v = f2bf(W_char[r * D_CHARE + c]);
            else if (c == 63)     v = 0x3F80;        // 1.0 bf16 (bias lane)
        }
        ws[j] = v;
    }
    int j2 = j - CHARP_U16;
    if (j2 >= 0 && j2 < WO_U16) {
        int o = j2 / KPAD, kg = j2 - o * KPAD;
        int kk = kg >> 6, c = kg & 63;
        float v = 0.f;
        if (o < OUT_CH) {
            if (c < D_CHARE)      v = conv_w[o * (D_CHARE * KSIZE) + c * KSIZE + kk];
            else if (kg == 191)   v = conv_b[o];     // bias rides K-slot 191
        }
        ws[CHARP_U16 + j2] = f2bf(v);
    }
}

__device__ __forceinline__ float4v fmax4(float4v a, float4v b) {
    float4v r;
    r[0] = fmaxf(a[0], b[0]); r[1] = fmaxf(a[1], b[1]);
    r[2] = fmaxf(a[2], b[2]); r[3] = fmaxf(a[3], b[3]);
    return r;
}

// A-frag read: word l15, LDS row `row`, true granule g (0..7); swizzle ^(row&7)^(word&7)
__device__ __forceinline__ short8 lda(const ushort* __restrict__ tile,
                                      int l15, int row, int g) {
    int pos = g ^ (row & 7) ^ (l15 & 7);
    return *(const short8*)&tile[l15 * 1024 + row * 64 + (pos << 3)];
}

// Persistent per-wave conv state across the phase barrier.
template <int NT>
struct ConvState {
    short8  B[NT][6];
    short8  w[8];
    float4v mx[NT];
};

template <int NT>
__device__ __forceinline__ void conv_init(ConvState<NT>& st, int tbase,
                                          int l15, int lg,
                                          const ushort* __restrict__ WO) {
    #pragma unroll
    for (int i = 0; i < NT; i++) {
        int col = (tbase + i) * 16 + l15;                 // <= 207 < MPAD
        #pragma unroll
        for (int s = 0; s < 6; s++)
            st.B[i][s] = *(const short8*)&WO[col * KPAD + s * 32 + lg * 8];
    }
}

// run pp-iterations [PP0, PP1); window loaded at PP0==0; slides prefetch rows 2pp+4/5
template <int NT, int PP0, int PP1>
__device__ __forceinline__ void conv_run(ConvState<NT>& st, int l15, int lg,
                                         const ushort* __restrict__ tile) {
    if (PP0 == 0) {
        #pragma unroll
        for (int rr = 0; rr < 4; rr++) {
            st.w[rr * 2]     = lda(tile, l15, rr, lg);
            st.w[rr * 2 + 1] = lda(tile, l15, rr, 4 + lg);
        }
    }
    #pragma unroll
    for (int pp = PP0; pp < PP1; pp++) {                  // positions p=2pp, q=2pp+1
        float4v ap[NT], aq[NT];
        #pragma unroll
        for (int i = 0; i < NT; i++) { ap[i] = (float4v){0,0,0,0}; aq[i] = (float4v){0,0,0,0}; }
        #pragma unroll
        for (int s = 0; s < 6; s++) {
            #pragma unroll
            for (int i = 0; i < NT; i++) {
                ap[i] = __builtin_amdgcn_mfma_f32_16x16x32_bf16(st.w[s],     st.B[i][s], ap[i], 0, 0, 0);
                aq[i] = __builtin_amdgcn_mfma_f32_16x16x32_bf16(st.w[s + 2], st.B[i][s], aq[i], 0, 0, 0);
            }
        }
        #pragma unroll
        for (int i = 0; i < NT; i++) {
            float4v m2 = fmax4(ap[i], aq[i]);
            st.mx[i] = (pp == 0) ? m2 : fmax4(st.mx[i], m2);
        }
        if (pp < 6) {                                     // slide window by 2 rows
            #pragma unroll
            for (int j = 0; j < 4; j++) st.w[j] = st.w[j + 4];
            const int r0 = 2 * pp + 4;
            st.w[4] = lda(tile, l15, r0,     lg);
            st.w[5] = lda(tile, l15, r0,     4 + lg);
            st.w[6] = lda(tile, l15, r0 + 1, lg);
            st.w[7] = lda(tile, l15, r0 + 1, 4 + lg);
        }
    }
}

template <int NT>
__device__ __forceinline__ void conv_store(const ConvState<NT>& st, int tbase,
                                           int l15, int lg,
                                           float* __restrict__ out, int block0) {
    #pragma unroll
    for (int i = 0; i < NT; i++) {
        int col = (tbase + i) * 16 + l15;
        if (col < OUT_CH) {
            #pragma unroll
            for (int j = 0; j < 4; j++)
                out[(size_t)(block0 + lg * 4 + j) * D_OUT + D_WORDE + col] = st.mx[i][j];
        }
    }
}

// ---------- uniform 512-thread block:
// stage(rows0-7) | bar | stage(rows8-15) + conv pp0..1 | bar | conv pp2..6 | store
// (pp0..1 slides touch rows <= 7 only; pp=2's slide to rows 8,9 is post-barrier)
__global__ void __launch_bounds__(512)
fused_kernel(const int* __restrict__ words, const int* __restrict__ chars,
             const float* __restrict__ W_word, const ushort* __restrict__ ws,
             float* __restrict__ out) {
    __shared__ __align__(16) ushort tile[TILE_U16];   // 32 KB

    const int tid  = threadIdx.x;
    const int lane = tid & 63;
    const int wave = tid >> 6;          // 0..7
    const int l15  = lane & 15;
    const int lg   = lane >> 4;

    const ushort* __restrict__ charP = ws;
    const ushort* __restrict__ WO    = ws + CHARP_U16;
    const int block0 = blockIdx.x * WPB;

    // ---- per-wave staging ids (words {2w, 2w+1}), swizzled source granule
    int ids_[2];
    int srcg_[2];
    #pragma unroll
    for (int ww = 0; ww < 2; ww++) {
        const int wl = wave * 2 + ww;
        const int m  = block0 + wl;
        const int* __restrict__ cbase = chars + ((m & 63) * SENT + (m >> 6)) * WLEN;
        srcg_[ww] = (lane & 7) ^ ((lane >> 3) & 7) ^ (wl & 7);
        ids_[ww] = cbase[(lane >> 3)];                     // rows 0..7 id
    }
    // phase A: stage rows 0..7 of both words
    #pragma unroll
    for (int ww = 0; ww < 2; ww++) {
        const int wl = wave * 2 + ww;
        GLOAD16(charP + ids_[ww] * 64 + (srcg_[ww] << 3), &tile[wl * 1024]);
    }
    // fetch s=1 ids (overlaps phase-A drain)
    int ids1_[2];
    #pragma unroll
    for (int ww = 0; ww < 2; ww++) {
        const int m = block0 + wave * 2 + ww;
        ids1_[ww] = chars[((m & 63) * SENT + (m >> 6)) * WLEN + 8 + (lane >> 3)];
    }
    __syncthreads();                    // rows 0..7 of all 16 words visible

    // phase B: issue rows 8..15 stage; compute pp=0..1 (reads+slides rows <= 7)
    #pragma unroll
    for (int ww = 0; ww < 2; ww++) {
        const int wl = wave * 2 + ww;
        GLOAD16(charP + ids1_[ww] * 64 + (srcg_[ww] << 3), &tile[wl * 1024 + 512]);
    }

    if (wave < 6) {
        ConvState<2> st;
        conv_init<2>(st, 2 * wave, l15, lg, WO);
        conv_run<2, 0, 2>(st, l15, lg, tile);             // pp=0..1: rows <= 7
        __syncthreads();                                  // rows 8..15 visible
        conv_run<2, 2, 7>(st, l15, lg, tile);             // pp=2..6
        conv_store<2>(st, 2 * wave, l15, lg, out, block0);
    } else if (wave == 6) {
        ConvState<1> st;
        conv_init<1>(st, 12, l15, lg, WO);
        conv_run<1, 0, 2>(st, l15, lg, tile);
        __syncthreads();
        conv_run<1, 2, 7>(st, l15, lg, tile);
        conv_store<1>(st, 12, l15, lg, out, block0);
    } else {
        // ---- emb wave: 8 rows before the barrier-join, 8 after
        const bool tail = lane < (75 - 64);
        #pragma unroll 1
        for (int r4 = 0; r4 < 2; r4++) {
            const int m0 = block0 + r4 * 4;
            float4v e0[4], e1[4];
            #pragma unroll
            for (int j = 0; j < 4; j++) {
                const float4v* __restrict__ src =
                    (const float4v*)(W_word + (size_t)words[m0 + j] * D_WORDE);
                e0[j] = src[lane];
                e1[j] = tail ? src[64 + lane] : (float4v){0, 0, 0, 0};
            }
            #pragma unroll
            for (int j = 0; j < 4; j++) {
                float4v* __restrict__ dst = (float4v*)(out + (size_t)(m0 + j) * D_OUT);
                dst[lane] = e0[j];
                if (tail) dst[64 + lane] = e1[j];
            }
        }
        __syncthreads();                                  // join the phase barrier
        #pragma unroll 1
        for (int r4 = 2; r4 < 4; r4++) {
            const int m0 = block0 + r4 * 4;
            float4v e0[4], e1[4];
            #pragma unroll
            for (int j = 0; j < 4; j++) {
                const float4v* __restrict__ src =
                    (const float4v*)(W_word + (size_t)words[m0 + j] * D_WORDE);
                e0[j] = src[lane];
                e1[j] = tail ? src[64 + lane] : (float4v){0, 0, 0, 0};
            }
            #pragma unroll
            for (int j = 0; j < 4; j++) {
                float4v* __restrict__ dst = (float4v*)(out + (size_t)(m0 + j) * D_OUT);
                dst[lane] = e0[j];
                if (tail) dst[64 + lane] = e1[j];
            }
        }
    }
}

// ---------- fallbacks (tiny ws): round-1 proven kernels ----------
__global__ void __launch_bounds__(256)
word_emb_kernel(const int* __restrict__ words, const float* __restrict__ W_word,
                float* __restrict__ out) {
    int wave = threadIdx.x >> 6, lane = threadIdx.x & 63;
    int m = blockIdx.x * 4 + wave;
    int idx = words[m];
    const float* __restrict__ src = W_word + (size_t)idx * D_WORDE;
    float* __restrict__ dst = out + (size_t)m * D_OUT;
    for (int j = lane; j < D_WORDE; j += 64) dst[j] = src[j];
}

__global__ void __launch_bounds__(256)
char_conv_f32_kernel(const int* __restrict__ chars, const float* __restrict__ W_char,
                     const float* __restrict__ conv_w, const float* __restrict__ conv_b,
                     float* __restrict__ out) {
    __shared__ __align__(16) float xs[D_CHARE * WLEN];
    __shared__ int ids[WLEN];
    int m = blockIdx.x, s = m >> 6, b = m & 63, tid = threadIdx.x;
    if (tid < WLEN) ids[tid] = chars[(b * SENT + s) * WLEN + tid];
    __syncthreads();
    for (int e = tid; e < D_CHARE * WLEN; e += 256) {
        int c = e >> 4, l = e & 15;
        xs[e] = W_char[ids[l] * D_CHARE + c];
    }
    __syncthreads();
    if (tid < OUT_CH) {
        float acc[NPOS];
        #pragma unroll
        for (int p = 0; p < NPOS; p++) acc[p] = 0.f;
        const float4* xs4 = (const float4*)xs;
        for (int c = 0; c < D_CHARE; c++) {
            float4 a0 = xs4[c*4+0], a1 = xs4[c*4+1], a2 = xs4[c*4+2], a3 = xs4[c*4+3];
            float xr[WLEN] = {a0.x,a0.y,a0.z,a0.w, a1.x,a1.y,a1.z,a1.w,
                              a2.x,a2.y,a2.z,a2.w, a3.x,a3.y,a3.z,a3.w};
            #pragma unroll
            for (int k = 0; k < KSIZE; k++) {
                float wv = conv_w[tid * (D_CHARE * KSIZE) + c * KSIZE + k];
                #pragma unroll
                for (int p = 0; p < NPOS; p++) acc[p] = fmaf(wv, xr[p + k], acc[p]);
            }
        }
        float mx = acc[0];
        #pragma unroll
        for (int p = 1; p < NPOS; p++) mx = fmaxf(mx, acc[p]);
        out[(size_t)m * D_OUT + D_WORDE + tid] = mx + conv_b[tid];
    }
}

extern "C" void kernel_launch(void* const* d_in, const int* in_sizes, int n_in,
                              void* d_out, int out_size, void* d_ws, size_t ws_size,
                              hipStream_t stream) {
    const int*   words  = (const int*)d_in[0];
    const int*   chars  = (const int*)d_in[1];
    const float* W_word = (const float*)d_in[2];
    const float* W_char = (const float*)d_in[3];
    const float* conv_w = (const float*)d_in[4];
    const float* conv_b = (const float*)d_in[5];
    float* out = (float*)d_out;

    if (ws_size >= WS_NEED) {
        ushort* ws = (ushort*)d_ws;
        hipLaunchKernelGGL(prep_kernel,
                           dim3((CHARP_U16 + WO_U16 + 255) / 256), dim3(256), 0, stream,
                           W_char, conv_w, conv_b, ws);
        hipLaunchKernelGGL(fused_kernel, dim3(CONV_BLOCKS), dim3(512), 0, stream,
                           words, chars, W_word, ws, out);
    } else {
        hipLaunchKernelGGL(word_emb_kernel, dim3(NWORDS / 4), dim3(256), 0, stream,
                           words, W_word, out);
        hipLaunchKernelGGL(char_conv_f32_kernel, dim3(NWORDS), dim3(256), 0, stream,
                           chars, W_char, conv_w, conv_b, out);
    }
}